// Round 6
// baseline (606.260 us; speedup 1.0000x reference)
//
#include <hip/hip_runtime.h>

// Problem constants
#define NPG   39
#define NGRAPH 8192
#define EPG   312           // input edges per graph
#define EDG   351           // + 39 self loops
#define E0    2555904       // total input edges (8192*312)
#define FDIM  4560
#define KP    4608          // padded K for bf16 GEMM (multiple of 128)
#define BT    256

typedef __bf16 bf16x8 __attribute__((ext_vector_type(8)));
typedef float  f32x4  __attribute__((ext_vector_type(4)));

__device__ __forceinline__ unsigned short f2b(float f) {
  unsigned int u = __float_as_uint(f);
  u += 0x7fffu + ((u >> 16) & 1u);            // RNE to bf16
  return (unsigned short)(u >> 16);
}
__device__ __forceinline__ float b2f(unsigned short u) {
  return __uint_as_float((unsigned int)u << 16);
}
// monotone float<->uint for atomicMax on LDS
__device__ __forceinline__ unsigned int fmono(float f) {
  unsigned int u = __float_as_uint(f);
  return (u & 0x80000000u) ? ~u : (u | 0x80000000u);
}
__device__ __forceinline__ float funmono(unsigned int u) {
  u = (u & 0x80000000u) ? (u & 0x7fffffffu) : ~u;
  return __uint_as_float(u);
}
__device__ __forceinline__ void split_store(float v, unsigned short* hi,
                                            unsigned short* lo, int i) {
  unsigned short h = f2b(v);
  hi[i] = h;
  lo[i] = f2b(v - b2f(h));
}

// ==================== GAT weight prep: hi/lo bf16 B-layout + folded attn ====
// wtL: [(NT1*16) rows][WS cols]; row o<Fo: W^T[o][k]; row Fo: (W@as)[k];
// row Fo+1: (W@ad)[k]; other rows/cols zero. hi/lo split pair per layer.
__global__ __launch_bounds__(256) void prep_wt(
    const float* __restrict__ W1, const float* __restrict__ as1, const float* __restrict__ ad1,
    const float* __restrict__ W2, const float* __restrict__ as2, const float* __restrict__ ad2,
    const float* __restrict__ W3, const float* __restrict__ as3, const float* __restrict__ ad3,
    const float* __restrict__ W4, const float* __restrict__ as4, const float* __restrict__ ad4,
    unsigned short* __restrict__ w1h, unsigned short* __restrict__ w1l,
    unsigned short* __restrict__ w2h, unsigned short* __restrict__ w2l,
    unsigned short* __restrict__ w3h, unsigned short* __restrict__ w3l,
    unsigned short* __restrict__ w4h, unsigned short* __restrict__ w4l) {
  const int tid = threadIdx.x;
  // wt1 [16][32]  (Fi=1, Fo=8)
  for (int i = tid; i < 16 * 32; i += 256) {
    int r = i >> 5, c = i & 31;
    float v = 0.f;
    if (c == 0) {
      if (r < 8) v = W1[r];
      else if (r == 8)  { float s = 0; for (int o = 0; o < 8; ++o) s += W1[o] * as1[o]; v = s; }
      else if (r == 9)  { float s = 0; for (int o = 0; o < 8; ++o) s += W1[o] * ad1[o]; v = s; }
    }
    split_store(v, w1h, w1l, i);
  }
  // wt2 [80][32]  (Fi=8, Fo=64)
  for (int i = tid; i < 80 * 32; i += 256) {
    int r = i >> 5, c = i & 31;
    float v = 0.f;
    if (c < 8) {
      if (r < 64) v = W2[c * 64 + r];
      else if (r == 64) { float s = 0; for (int o = 0; o < 64; ++o) s += W2[c * 64 + o] * as2[o]; v = s; }
      else if (r == 65) { float s = 0; for (int o = 0; o < 64; ++o) s += W2[c * 64 + o] * ad2[o]; v = s; }
    }
    split_store(v, w2h, w2l, i);
  }
  // wt3 [48][64]  (Fi=64, Fo=32)
  for (int i = tid; i < 48 * 64; i += 256) {
    int r = i >> 6, c = i & 63;
    float v = 0.f;
    if (r < 32) v = W3[c * 32 + r];
    else if (r == 32) { float s = 0; for (int o = 0; o < 32; ++o) s += W3[c * 32 + o] * as3[o]; v = s; }
    else if (r == 33) { float s = 0; for (int o = 0; o < 32; ++o) s += W3[c * 32 + o] * ad3[o]; v = s; }
    split_store(v, w3h, w3l, i);
  }
  // wt4 [16][32]  (Fi=32, Fo=9)
  for (int i = tid; i < 16 * 32; i += 256) {
    int r = i >> 5, c = i & 31;
    float v = 0.f;
    if (r < 9) v = W4[c * 9 + r];
    else if (r == 9)  { float s = 0; for (int o = 0; o < 9; ++o) s += W4[c * 9 + o] * as4[o]; v = s; }
    else if (r == 10) { float s = 0; for (int o = 0; o < 9; ++o) s += W4[c * 9 + o] * ad4[o]; v = s; }
    split_store(v, w4h, w4l, i);
  }
}

// =========================== fused GAT layer (hi/lo MFMA) ====================
// hA: [48][72] node features (A-layout), hi/lo pair, pads zero.
// hT: [64][72] H1 transposed (row=o, col=s), hi/lo pair, cols>=48 zero.
// Pb: [48][72] attention matrix, hi/lo pair; Pm (f32 [39][40]) aliases Pbhi.
template<int Fi, int Fo, int WS>
__device__ __forceinline__ void gat_layer(
    unsigned short* hAhi, unsigned short* hAlo,
    unsigned short* hThi, unsigned short* hTlo,
    unsigned short* Pbhi, unsigned short* Pblo,
    float* snb, float* dnb, float* den,
    unsigned int* maxu, unsigned int* poolu, float* blS,
    const unsigned int* el,
    const unsigned short* __restrict__ wth, const unsigned short* __restrict__ wtl,
    const float* __restrict__ bias,
    unsigned short* __restrict__ f_row, int res_off, int out_off, int tid) {
  constexpr int KS1 = (Fi + 31) / 32;
  constexpr int NT1 = (Fo + 2 + 15) / 16;
  constexpr int NT4 = (Fo + 15) / 16;
  const int lane = tid & 63, wave = tid >> 6;
  const int rm = lane & 15, q = lane >> 4;
  const int q8 = q * 8, q4 = q * 4;
  float* Pm = (float*)Pbhi;
  const f32x4 z = {0.f, 0.f, 0.f, 0.f};

  __syncthreads();                      // B1: hA ready (prev P4 / init)
  if (tid < 64) blS[tid] = (tid < Fo) ? bias[tid] : 0.f;
  else if (tid < 128) poolu[tid - 64] = 0u;
  else if (tid < 168) maxu[tid - 128] = 0u;
  // ---- P1: [H1 | sn | dn] = hA @ wt^T, 3-term hi/lo MFMA ----
  for (int t = wave; t < 3 * NT1; t += 4) {
    int mt = t / NT1, nt = t % NT1;
    f32x4 acc = z;
#pragma unroll
    for (int k = 0; k < KS1; ++k) {
      int ao = (mt * 16 + rm) * 72 + k * 32 + q8;
      int bo = (nt * 16 + rm) * WS + k * 32 + q8;
      bf16x8 ah = *(const bf16x8*)&hAhi[ao];
      bf16x8 al = *(const bf16x8*)&hAlo[ao];
      bf16x8 bh = *(const bf16x8*)&wth[bo];
      bf16x8 bl = *(const bf16x8*)&wtl[bo];
      acc = __builtin_amdgcn_mfma_f32_16x16x32_bf16(ah, bh, acc, 0, 0, 0);
      acc = __builtin_amdgcn_mfma_f32_16x16x32_bf16(ah, bl, acc, 0, 0, 0);
      acc = __builtin_amdgcn_mfma_f32_16x16x32_bf16(al, bh, acc, 0, 0, 0);
    }
    int o = nt * 16 + rm, s0 = mt * 16 + q4;
    if (o < Fo) {                       // write H1^T hi/lo (B-layout for P4)
      ushort4 ph, pl;
      unsigned short h;
      h = f2b(acc[0]); ph.x = h; pl.x = f2b(acc[0] - b2f(h));
      h = f2b(acc[1]); ph.y = h; pl.y = f2b(acc[1] - b2f(h));
      h = f2b(acc[2]); ph.z = h; pl.z = f2b(acc[2] - b2f(h));
      h = f2b(acc[3]); ph.w = h; pl.w = f2b(acc[3] - b2f(h));
      *(ushort4*)&hThi[o * 72 + s0] = ph;
      *(ushort4*)&hTlo[o * 72 + s0] = pl;
    } else if (o == Fo) {
      snb[s0] = acc[0]; snb[s0 + 1] = acc[1]; snb[s0 + 2] = acc[2]; snb[s0 + 3] = acc[3];
    } else if (o == Fo + 1) {
      dnb[s0] = acc[0]; dnb[s0 + 1] = acc[1]; dnb[s0 + 2] = acc[2]; dnb[s0 + 3] = acc[3];
    }
  }
  __syncthreads();                      // B2: hT/snb/dnb ready; Pb dead
  // ---- P3a: zero Pm/den; per-dst max of leaky-relu logits ----
  for (int i = tid; i < 390; i += BT) *(f32x4*)&Pm[4 * i] = z;
  if (tid < 48) den[tid] = 0.f;
  for (int k = tid; k < EDG; k += BT) {
    unsigned int e2 = el[k];
    int s = e2 & 0xffffu, d = e2 >> 16;
    float e = snb[s] + dnb[d];
    e = (e >= 0.f) ? e : 0.2f * e;
    atomicMax(&maxu[d], fmono(e));
  }
  __syncthreads();                      // B3
  // ---- P3b: scatter exp into dense Pm (f32) ----
  for (int k = tid; k < EDG; k += BT) {
    unsigned int e2 = el[k];
    int s = e2 & 0xffffu, d = e2 >> 16;
    float e = snb[s] + dnb[d];
    e = (e >= 0.f) ? e : 0.2f * e;
    float w = __expf(e - funmono(maxu[d]));
    atomicAdd(&Pm[d * 40 + s], w);
  }
  __syncthreads();                      // B4
  // ---- conv: Pm -> Pb hi/lo (two-phase: Pm aliases Pbhi); den = rowsum ----
  f32x4 pv[3];
#pragma unroll
  for (int ii = 0; ii < 3; ++ii) {
    int i = tid + ii * BT;              // 768 items = 48 rows x 16 col-chunks
    int r = i >> 4, c = i & 15;
    f32x4 v = z;
    if (r < NPG && c < 10) {
      v = *(const f32x4*)&Pm[r * 40 + 4 * c];
      atomicAdd(&den[r], (v.x + v.y) + (v.z + v.w));
    }
    pv[ii] = v;
  }
  __syncthreads();                      // B5: all Pm reads done
#pragma unroll
  for (int ii = 0; ii < 3; ++ii) {
    int i = tid + ii * BT;
    int r = i >> 4, c = i & 15;
    ushort4 ph, pl;
    unsigned short h;
    h = f2b(pv[ii].x); ph.x = h; pl.x = f2b(pv[ii].x - b2f(h));
    h = f2b(pv[ii].y); ph.y = h; pl.y = f2b(pv[ii].y - b2f(h));
    h = f2b(pv[ii].z); ph.z = h; pl.z = f2b(pv[ii].z - b2f(h));
    h = f2b(pv[ii].w); ph.w = h; pl.w = f2b(pv[ii].w - b2f(h));
    *(ushort4*)&Pbhi[r * 72 + 4 * c] = ph;
    *(ushort4*)&Pblo[r * 72 + 4 * c] = pl;
  }
  __syncthreads();                      // B5b: Pb ready
  // ---- P4: out = Pb @ hT^T, 3-term hi/lo MFMA; fused norm+bias+relu+pool ---
  for (int t = wave; t < 3 * NT4; t += 4) {
    int mt = t / NT4, nt = t % NT4;
    f32x4 acc = z;
#pragma unroll
    for (int k = 0; k < 2; ++k) {
      int ao = (mt * 16 + rm) * 72 + k * 32 + q8;
      int bo = (nt * 16 + rm) * 72 + k * 32 + q8;
      bf16x8 ah = *(const bf16x8*)&Pbhi[ao];
      bf16x8 al = *(const bf16x8*)&Pblo[ao];
      bf16x8 bh = *(const bf16x8*)&hThi[bo];
      bf16x8 bl = *(const bf16x8*)&hTlo[bo];
      acc = __builtin_amdgcn_mfma_f32_16x16x32_bf16(ah, bh, acc, 0, 0, 0);
      acc = __builtin_amdgcn_mfma_f32_16x16x32_bf16(ah, bl, acc, 0, 0, 0);
      acc = __builtin_amdgcn_mfma_f32_16x16x32_bf16(al, bh, acc, 0, 0, 0);
    }
    int o = nt * 16 + rm, d0 = mt * 16 + q4;
    float bv = blS[o];
    float pmax = 0.f;
#pragma unroll
    for (int v = 0; v < 4; ++v) {
      int d = d0 + v;
      float inv = 1.f / (den[d] + 1e-16f);
      float val = fmaxf(acc[v] * inv + bv, 0.f);
      if (d < NPG && o < Fo) {
        unsigned short h = f2b(val);
        hAhi[d * 72 + o] = h;                 // next layer input hi
        hAlo[d * 72 + o] = f2b(val - b2f(h)); // next layer input lo
        f_row[res_off + d * Fo + o] = h;      // res feature (bf16)
        pmax = fmaxf(pmax, val);
      }
    }
    pmax = fmaxf(pmax, __shfl_xor(pmax, 16, 64));
    pmax = fmaxf(pmax, __shfl_xor(pmax, 32, 64));
    if (q == 0 && o < Fo) atomicMax(&poolu[o], __float_as_uint(pmax)); // >=0
  }
  __syncthreads();                      // B6
  if (tid < Fo) f_row[out_off + tid] = f2b(__uint_as_float(poolu[tid]));
}

__global__ __launch_bounds__(BT, 3) void gat_fused(
    const float* __restrict__ x, const int* __restrict__ ei,
    const float* __restrict__ b1, const float* __restrict__ b2,
    const float* __restrict__ b3, const float* __restrict__ b4,
    const unsigned short* __restrict__ w1h, const unsigned short* __restrict__ w1l,
    const unsigned short* __restrict__ w2h, const unsigned short* __restrict__ w2l,
    const unsigned short* __restrict__ w3h, const unsigned short* __restrict__ w3l,
    const unsigned short* __restrict__ w4h, const unsigned short* __restrict__ w4l,
    unsigned short* __restrict__ f) {
  __shared__ alignas(16) unsigned short hAhi[48 * 72], hAlo[48 * 72];
  __shared__ alignas(16) unsigned short hThi[64 * 72], hTlo[64 * 72];
  __shared__ alignas(16) unsigned short Pbhi[48 * 72], Pblo[48 * 72];
  __shared__ alignas(16) float snb[48], dnb[48], den[48];
  __shared__ alignas(16) unsigned int maxu[40];
  __shared__ alignas(16) unsigned int poolu[64];
  __shared__ alignas(16) float blS[64];
  __shared__ alignas(16) unsigned int el[EDG + 1];

  const int b = blockIdx.x;
  const int tid = threadIdx.x;
  const int* srcg = ei + (size_t)b * EPG;
  const int* dstg = ei + E0 + (size_t)b * EPG;
  unsigned short* f_row = f + (size_t)b * KP;
  const int base = b * NPG;

  // init: zero all LDS tensors, build edge list, pad f_row, out0
  const uint4 z4 = {0u, 0u, 0u, 0u};
  for (int i = tid; i < 432; i += BT) {
    ((uint4*)hAhi)[i] = z4; ((uint4*)hAlo)[i] = z4;
    ((uint4*)Pbhi)[i] = z4; ((uint4*)Pblo)[i] = z4;
  }
  for (int i = tid; i < 576; i += BT) {
    ((uint4*)hThi)[i] = z4; ((uint4*)hTlo)[i] = z4;
  }
  for (int e = tid; e < EDG; e += BT) {
    int s, d;
    if (e < EPG) { s = srcg[e] - base; d = dstg[e] - base; } else { s = d = e - EPG; }
    s = min(max(s, 0), NPG - 1);
    d = min(max(d, 0), NPG - 1);
    el[e] = (unsigned int)s | ((unsigned int)d << 16);
  }
  for (int i = tid; i < KP - FDIM; i += BT) f_row[FDIM + i] = 0;  // bf16 zero
  if (tid < 64) {                       // out0 = max over raw x (from global)
    float v = (tid < NPG) ? x[(size_t)base + tid] : -3.4e38f;
#pragma unroll
    for (int m = 32; m > 0; m >>= 1) v = fmaxf(v, __shfl_xor(v, m, 64));
    if (tid == 0) f_row[4446] = f2b(v);
  }
  __syncthreads();                      // zeroing done before x writes
  for (int n = tid; n < NPG; n += BT) {
    float v = x[(size_t)base + n];
    unsigned short h = f2b(v);
    hAhi[n * 72] = h;
    hAlo[n * 72] = f2b(v - b2f(h));
    f_row[n] = h;
  }

  //        Fi  Fo  WS
  gat_layer<1,  8,  32>(hAhi, hAlo, hThi, hTlo, Pbhi, Pblo, snb, dnb, den, maxu, poolu, blS, el, w1h, w1l, b1, f_row, 39,   4447, tid);
  gat_layer<8,  64, 32>(hAhi, hAlo, hThi, hTlo, Pbhi, Pblo, snb, dnb, den, maxu, poolu, blS, el, w2h, w2l, b2, f_row, 351,  4455, tid);
  gat_layer<64, 32, 64>(hAhi, hAlo, hThi, hTlo, Pbhi, Pblo, snb, dnb, den, maxu, poolu, blS, el, w3h, w3l, b3, f_row, 2847, 4519, tid);
  gat_layer<32, 9,  32>(hAhi, hAlo, hThi, hTlo, Pbhi, Pblo, snb, dnb, den, maxu, poolu, blS, el, w4h, w4l, b4, f_row, 4095, 4551, tid);
}

// ================= weight transpose + bf16 cast (per launch) =================
__global__ __launch_bounds__(256) void tcast(const float* __restrict__ in,
                                             unsigned short* __restrict__ out,
                                             int K, int NN, int Kpad) {
  __shared__ float tile[64 * 65];
  const int k0 = blockIdx.x * 64, n0 = blockIdx.y * 64;
  const int tid = threadIdx.x;
#pragma unroll
  for (int i = 0; i < 16; ++i) {
    int idx = i * 256 + tid;
    int r = idx >> 6, c = idx & 63;
    int k = k0 + r;
    tile[r * 65 + c] = (k < K) ? in[(size_t)k * NN + n0 + c] : 0.f;
  }
  __syncthreads();
#pragma unroll
  for (int i = 0; i < 16; ++i) {
    int idx = i * 256 + tid;
    int r = idx >> 6, c = idx & 63;    // r: n-offset, c: k-offset
    out[(size_t)(n0 + r) * Kpad + k0 + c] = f2b(tile[c * 65 + r]);
  }
}

// =========================== bf16 MFMA GEMM ===========================
template<bool OUT_BF16>
__global__ __launch_bounds__(256) void mfma_gemm(const unsigned short* __restrict__ A,
    const unsigned short* __restrict__ Bt, unsigned short* __restrict__ Cb,
    float* __restrict__ Cf, const float* __restrict__ bias, int K, int N) {
  __shared__ alignas(16) unsigned short As[128 * 32];
  __shared__ alignas(16) unsigned short Bs[128 * 32];
  const int tid = threadIdx.x;
  const int lane = tid & 63;
  const int wave = tid >> 6;
  const int wy = wave >> 1, wx = wave & 1;
  const int m0 = blockIdx.y * 128, n0 = blockIdx.x * 128;

  f32x4 acc[4][4];
  const f32x4 z = {0.f, 0.f, 0.f, 0.f};
#pragma unroll
  for (int i = 0; i < 4; ++i)
#pragma unroll
    for (int j = 0; j < 4; ++j) acc[i][j] = z;

  const int lr = lane >> 2;
  const int lc = (lane & 3) * 8;
  const int q8 = (lane >> 4) * 8;
  const int rm = lane & 15;

  for (int k0 = 0; k0 < K; k0 += 32) {
    __syncthreads();
#pragma unroll
    for (int t = 0; t < 2; ++t) {
      int r0 = wave * 32 + t * 16;
      const unsigned short* ga = A  + (size_t)(m0 + r0 + lr) * K + k0 + lc;
      const unsigned short* gb = Bt + (size_t)(n0 + r0 + lr) * K + k0 + lc;
      __builtin_amdgcn_global_load_lds(
          (const __attribute__((address_space(1))) unsigned int*)(const void*)ga,
          (__attribute__((address_space(3))) unsigned int*)(void*)&As[r0 * 32], 16, 0, 0);
      __builtin_amdgcn_global_load_lds(
          (const __attribute__((address_space(1))) unsigned int*)(const void*)gb,
          (__attribute__((address_space(3))) unsigned int*)(void*)&Bs[r0 * 32], 16, 0, 0);
    }
    __syncthreads();
    bf16x8 af[4], bfr[4];
#pragma unroll
    for (int i = 0; i < 4; ++i) {
      af[i]  = *(const bf16x8*)&As[(wy * 64 + i * 16 + rm) * 32 + q8];
      bfr[i] = *(const bf16x8*)&Bs[(wx * 64 + i * 16 + rm) * 32 + q8];
    }
#pragma unroll
    for (int i = 0; i < 4; ++i)
#pragma unroll
      for (int j = 0; j < 4; ++j)
        acc[i][j] = __builtin_amdgcn_mfma_f32_16x16x32_bf16(af[i], bfr[j], acc[i][j], 0, 0, 0);
  }
  const int q4 = (lane >> 4) * 4;
#pragma unroll
  for (int i = 0; i < 4; ++i) {
#pragma unroll
    for (int j = 0; j < 4; ++j) {
      int row = m0 + wy * 64 + i * 16 + q4;
      int col = n0 + wx * 64 + j * 16 + rm;
      float bv = bias[col];
#pragma unroll
      for (int v = 0; v < 4; ++v) {
        float val = fmaxf(acc[i][j][v] + bv, 0.f);
        if constexpr (OUT_BF16) Cb[(size_t)(row + v) * N + col] = f2b(val);
        else                    Cf[(size_t)(row + v) * N + col] = val;
      }
    }
  }
}

// =========================== final 128->9 layer ===========================
__global__ __launch_bounds__(256) void mlp3(const float* __restrict__ g2,
                                            const float* __restrict__ w3,
                                            const float* __restrict__ b3,
                                            float* __restrict__ out) {
  __shared__ float gs[64 * 130];
  __shared__ float ws3[128 * 9];
  const int r0 = blockIdx.x * 64;
  const int tid = threadIdx.x;
  for (int i = tid; i < 64 * 128; i += 256)
    gs[(i >> 7) * 130 + (i & 127)] = g2[(size_t)r0 * 128 + i];
  for (int i = tid; i < 128 * 9; i += 256) ws3[i] = w3[i];
  __syncthreads();
  for (int idx = tid; idx < 64 * 9; idx += 256) {
    int r = idx / 9, c = idx - r * 9;
    float acc = b3[c];
#pragma unroll 8
    for (int k = 0; k < 128; ++k) acc += gs[r * 130 + k] * ws3[k * 9 + c];
    out[(size_t)(r0 + r) * 9 + c] = acc;
  }
}

// =========================== launch ===========================
extern "C" void kernel_launch(void* const* d_in, const int* in_sizes, int n_in,
                              void* d_out, int out_size, void* d_ws, size_t ws_size,
                              hipStream_t stream) {
  const float* x   = (const float*)d_in[0];
  const int*   ei  = (const int*)d_in[1];
  const float* W1  = (const float*)d_in[3];
  const float* as1 = (const float*)d_in[4];
  const float* ad1 = (const float*)d_in[5];
  const float* b1  = (const float*)d_in[6];
  const float* W2  = (const float*)d_in[7];
  const float* as2 = (const float*)d_in[8];
  const float* ad2 = (const float*)d_in[9];
  const float* b2  = (const float*)d_in[10];
  const float* W3  = (const float*)d_in[11];
  const float* as3 = (const float*)d_in[12];
  const float* ad3 = (const float*)d_in[13];
  const float* b3  = (const float*)d_in[14];
  const float* W4  = (const float*)d_in[15];
  const float* as4 = (const float*)d_in[16];
  const float* ad4 = (const float*)d_in[17];
  const float* b4  = (const float*)d_in[18];
  const float* lw1 = (const float*)d_in[19];
  const float* lb1 = (const float*)d_in[20];
  const float* lw2 = (const float*)d_in[21];
  const float* lb2 = (const float*)d_in[22];
  const float* lw3 = (const float*)d_in[23];
  const float* lb3 = (const float*)d_in[24];
  float* out = (float*)d_out;

  // workspace carve-up (bf16 stored as u16); total ~106.2 MB
  unsigned short* f   = (unsigned short*)d_ws;            // [8192][4608] bf16
  unsigned short* w1t = f   + (size_t)NGRAPH * KP;        // [1024][4608] bf16
  unsigned short* w2t = w1t + (size_t)1024 * KP;          // [128][1024]  bf16
  unsigned short* g1  = w2t + (size_t)128 * 1024;         // [8192][1024] bf16
  float*          g2  = (float*)(g1 + (size_t)NGRAPH * 1024); // [8192][128] f32
  // GAT hi/lo weight buffers alias g2 head: consumed by gat_fused BEFORE
  // mfma_gemm<false> writes g2 (stream-ordered, safe)
  unsigned short* w1h = (unsigned short*)g2;   // 512
  unsigned short* w1l = w1h + 512;             // 512
  unsigned short* w2h = w1l + 512;             // 2560
  unsigned short* w2l = w2h + 2560;            // 2560
  unsigned short* w3h = w2l + 2560;            // 3072
  unsigned short* w3l = w3h + 3072;            // 3072
  unsigned short* w4h = w3l + 3072;            // 512
  unsigned short* w4l = w4h + 512;             // 512

  prep_wt<<<1, 256, 0, stream>>>(W1, as1, ad1, W2, as2, ad2,
                                 W3, as3, ad3, W4, as4, ad4,
                                 w1h, w1l, w2h, w2l, w3h, w3l, w4h, w4l);
  tcast<<<dim3(KP / 64, 1024 / 64), 256, 0, stream>>>(lw1, w1t, FDIM, 1024, KP);
  tcast<<<dim3(1024 / 64, 128 / 64), 256, 0, stream>>>(lw2, w2t, 1024, 128, 1024);

  gat_fused<<<NGRAPH, BT, 0, stream>>>(x, ei, b1, b2, b3, b4,
                                       w1h, w1l, w2h, w2l, w3h, w3l, w4h, w4l, f);

  mfma_gemm<true ><<<dim3(1024 / 128, NGRAPH / 128), 256, 0, stream>>>(
      f, w1t, g1, nullptr, lb1, KP, 1024);
  mfma_gemm<false><<<dim3(128 / 128, NGRAPH / 128), 256, 0, stream>>>(
      g1, w2t, nullptr, g2, lb2, 1024, 128);

  mlp3<<<NGRAPH / 64, 256, 0, stream>>>(g2, lw3, lb3, out);
}